// Round 7
// baseline (644.491 us; speedup 1.0000x reference)
//
#include <hip/hip_runtime.h>
#include <math.h>

#define Bc 2
#define Tc 2048
#define Dc 1024
#define Hc 16
#define HDc 64
#define Mc (Bc * Tc)   // 4096 rows

typedef __attribute__((ext_vector_type(4))) float f32x4;
typedef __attribute__((ext_vector_type(8))) short bf16x8;

__device__ __forceinline__ unsigned short f2bf(float f) {
  unsigned int u = __float_as_uint(f);
  u += 0x7fff + ((u >> 16) & 1);          // RNE
  return (unsigned short)(u >> 16);
}

__device__ __forceinline__ void gload16(const void* g, void* l) {
  __builtin_amdgcn_global_load_lds((const __attribute__((address_space(1))) unsigned int*)g,
                                   (__attribute__((address_space(3))) unsigned int*)l, 16, 0, 0);
}

// ---------- weight convert+transpose: W[K][N] f32 -> Wt[N][K] bf16 ----------
__global__ __launch_bounds__(256) void wconv_kernel(const float* __restrict__ W,
                                                    unsigned short* __restrict__ Wt,
                                                    int K, int N) {
  __shared__ float tile[64][65];
  const int t = threadIdx.x;
  const int kt = blockIdx.y * 64, nt = blockIdx.x * 64;
#pragma unroll
  for (int p = 0; p < 4; p++) {
    int kr = p * 16 + (t >> 4);
    int nc = (t & 15) * 4;
    float4 v = *(const float4*)&W[(size_t)(kt + kr) * N + nt + nc];
    tile[kr][nc] = v.x; tile[kr][nc + 1] = v.y; tile[kr][nc + 2] = v.z; tile[kr][nc + 3] = v.w;
  }
  __syncthreads();
  const int nr = t >> 2, kc = (t & 3) * 16;
  unsigned int u[8];
#pragma unroll
  for (int i = 0; i < 8; i++)
    u[i] = (unsigned int)f2bf(tile[kc + 2 * i][nr]) | ((unsigned int)f2bf(tile[kc + 2 * i + 1][nr]) << 16);
  uint4 w0; w0.x = u[0]; w0.y = u[1]; w0.z = u[2]; w0.w = u[3];
  uint4 w1; w1.x = u[4]; w1.y = u[5]; w1.z = u[6]; w1.w = u[7];
  *(uint4*)&Wt[(size_t)(nt + nr) * K + kt + kc] = w0;
  *(uint4*)&Wt[(size_t)(nt + nr) * K + kt + kc + 8] = w1;
}

// ---------- LayerNorm: fp32 in, bf16 out ----------
__global__ __launch_bounds__(256) void ln_kernel(const float* __restrict__ x,
                                                 const float* __restrict__ g,
                                                 const float* __restrict__ be,
                                                 unsigned short* __restrict__ out) {
  const int row = blockIdx.x;
  const int t = threadIdx.x;
  const float4* xp = (const float4*)(x + (size_t)row * Dc);
  float4 v = xp[t];
  float s = v.x + v.y + v.z + v.w;
  float s2 = v.x * v.x + v.y * v.y + v.z * v.z + v.w * v.w;
#pragma unroll
  for (int off = 32; off; off >>= 1) {
    s += __shfl_down(s, off);
    s2 += __shfl_down(s2, off);
  }
  __shared__ float rs[4], rs2[4];
  if ((t & 63) == 0) { rs[t >> 6] = s; rs2[t >> 6] = s2; }
  __syncthreads();
  float S = rs[0] + rs[1] + rs[2] + rs[3];
  float S2 = rs2[0] + rs2[1] + rs2[2] + rs2[3];
  float mean = S * (1.0f / Dc);
  float var = S2 * (1.0f / Dc) - mean * mean;
  float rstd = rsqrtf(var + 1e-5f);
  float4 gv = ((const float4*)g)[t];
  float4 bv = ((const float4*)be)[t];
  float o0 = (v.x - mean) * rstd * gv.x + bv.x;
  float o1 = (v.y - mean) * rstd * gv.y + bv.y;
  float o2 = (v.z - mean) * rstd * gv.z + bv.z;
  float o3 = (v.w - mean) * rstd * gv.w + bv.w;
  uint2 pk;
  pk.x = (unsigned int)f2bf(o0) | ((unsigned int)f2bf(o1) << 16);
  pk.y = (unsigned int)f2bf(o2) | ((unsigned int)f2bf(o3) << 16);
  *(uint2*)(out + (size_t)row * Dc + t * 4) = pk;
}

// ---------- bf16 MFMA GEMM: C[M,N] = A[M,K] @ Wt[N,K]^T, fused epilogue ----------
// flags: 1=+bias, 2=exact GELU, 4=+resid(fp32), 8=write bf16 to aux, 16=qkv split write
#define GBM 128
#define GBN 128
#define GBK 32

__global__ __launch_bounds__(256) void gemm_bf16(const unsigned short* __restrict__ A,
                                                 const unsigned short* __restrict__ Wt,
                                                 const float* __restrict__ bias,
                                                 const float* __restrict__ resid,
                                                 float* __restrict__ C,
                                                 unsigned short* __restrict__ aux,
                                                 int M, int N, int K, int flags) {
  __shared__ alignas(16) unsigned short As[GBM][GBK];   // 8 KB, row stride 64 B
  __shared__ alignas(16) unsigned short Bs[GBN][GBK];   // 8 KB (n-major)
  const int t = threadIdx.x;
  const int lane = t & 63, wave = t >> 6;
  const int wr = wave >> 1, wc = wave & 1;
  const int c = lane & 15, g = lane >> 4;
  const int row0 = blockIdx.y * GBM, col0 = blockIdx.x * GBN;

  f32x4 acc[4][4];
#pragma unroll
  for (int m = 0; m < 4; m++)
#pragma unroll
    for (int n = 0; n < 4; n++) acc[m][n] = (f32x4){0.f, 0.f, 0.f, 0.f};

  char* AsB = (char*)&As[0][0];
  char* BsB = (char*)&Bs[0][0];
  const int l0 = t, l1 = t + 256;
  const int lds0 = wave * 1024, lds1 = wave * 1024 + 4096;   // wave-uniform LDS bases

  for (int k0 = 0; k0 < K; k0 += GBK) {
    gload16(A + (size_t)(row0 + (l0 >> 2)) * K + k0 + (l0 & 3) * 8, AsB + lds0);
    gload16(A + (size_t)(row0 + (l1 >> 2)) * K + k0 + (l1 & 3) * 8, AsB + lds1);
    gload16(Wt + (size_t)(col0 + (l0 >> 2)) * K + k0 + (l0 & 3) * 8, BsB + lds0);
    gload16(Wt + (size_t)(col0 + (l1 >> 2)) * K + k0 + (l1 & 3) * 8, BsB + lds1);
    __syncthreads();
    bf16x8 af[4], bfv[4];
#pragma unroll
    for (int m = 0; m < 4; m++) af[m] = *(const bf16x8*)(AsB + (wr * 64 + m * 16 + c) * 64 + g * 16);
#pragma unroll
    for (int n = 0; n < 4; n++) bfv[n] = *(const bf16x8*)(BsB + (wc * 64 + n * 16 + c) * 64 + g * 16);
#pragma unroll
    for (int m = 0; m < 4; m++)
#pragma unroll
      for (int n = 0; n < 4; n++)
        acc[m][n] = __builtin_amdgcn_mfma_f32_16x16x32_bf16(af[m], bfv[n], acc[m][n], 0, 0, 0);
    __syncthreads();
  }

#pragma unroll
  for (int m = 0; m < 4; m++) {
    const int row = row0 + wr * 64 + m * 16 + g * 4;
#pragma unroll
    for (int n = 0; n < 4; n++) {
      const int col = col0 + wc * 64 + n * 16 + c;
      const float bi = (flags & 1) ? bias[col] : 0.0f;
#pragma unroll
      for (int r = 0; r < 4; r++) {
        float v = acc[m][n][r] + bi;
        if (flags & 2) v = 0.5f * v * (1.0f + erff(v * 0.70710678118654752f));
        if (flags & 4) v += resid[(size_t)(row + r) * N + col];
        if (flags & 16) {
          // qkv split: Q at 0, K at +4M, V (row-major) at +8M, all [bh][t][d] bf16
          int rr = row + r;
          int b = rr >> 11, tt = rr & 2047;
          int s = col >> 10, wcol = col & 1023;
          int h = wcol >> 6, f = wcol & 63;
          int bh = b * Hc + h;
          aux[(size_t)s * 4194304 + (size_t)bh * Tc * HDc + (size_t)tt * HDc + f] = f2bf(v);
        } else if (flags & 8) {
          aux[(size_t)(row + r) * N + col] = f2bf(v);
        } else {
          C[(size_t)(row + r) * N + col] = v;
        }
      }
    }
  }
}

// ---------- V transpose: V[bh][t][d] -> Vt[bh][d][t], 64x64 LDS tiles ----------
__global__ __launch_bounds__(256) void vtrans(const unsigned short* __restrict__ V,
                                              unsigned short* __restrict__ Vt) {
  __shared__ unsigned short tile[64][72];
  const int bh = blockIdx.y, t0 = blockIdx.x * 64;
  const int t = threadIdx.x;
  const int r8 = t >> 3, c8 = (t & 7) * 8;
#pragma unroll
  for (int p = 0; p < 2; p++) {
    int rr = p * 32 + r8;
    *(uint4*)&tile[rr][c8] = *(const uint4*)&V[((size_t)bh * Tc + t0 + rr) * HDc + c8];
  }
  __syncthreads();
#pragma unroll
  for (int p = 0; p < 2; p++) {
    int d = p * 32 + r8;
    unsigned short tmp[8];
#pragma unroll
    for (int j = 0; j < 8; j++) tmp[j] = tile[c8 + j][d];
    *(uint4*)&Vt[((size_t)bh * HDc + d) * Tc + t0 + c8] = *(uint4*)tmp;
  }
}

// ---------- MFMA flash attention v3: XCD-local bh, register K ping-pong ----------
// Qb,Kb: [32 bh][2048][64] bf16 ; Vt: [32 bh][64][2048] bf16 ; Ob: [B][T][D] bf16
__global__ __launch_bounds__(256, 4) void fattn(const unsigned short* __restrict__ Qb,
                                                const unsigned short* __restrict__ Kb,
                                                const unsigned short* __restrict__ Vt,
                                                unsigned short* __restrict__ Ob) {
  __shared__ alignas(16) unsigned short P[4][16][64];   // 8 KB, 128 B rows, XOR-swizzled
  const int t = threadIdx.x, wave = t >> 6, lane = t & 63;
  const int c = lane & 15, g = lane >> 4;
  const int bid = blockIdx.x;
  // XCD-aware: bid%8 selects a group of 4 bh, so each XCD's L2 holds only 4 bh of K/V (2 MB)
  const int bh = ((bid & 7) << 2) | ((bid >> 3) & 3);
  const int qt = bid >> 5;
  const int q0 = qt * 64 + wave * 16;

  const unsigned short* Qp = Qb + ((size_t)bh * Tc + q0) * HDc;
  const unsigned short* Kp = Kb + (size_t)bh * Tc * HDc;
  const unsigned short* Vp = Vt + (size_t)bh * HDc * Tc;
  char* Pw = (char*)&P[wave][0][0];

  const bf16x8 qf0 = *(const bf16x8*)(Qp + c * HDc + g * 8);
  const bf16x8 qf1 = *(const bf16x8*)(Qp + c * HDc + 32 + g * 8);

  const f32x4 z = {0.f, 0.f, 0.f, 0.f};
  f32x4 o[4] = {z, z, z, z};
  float m[4] = {-3e38f, -3e38f, -3e38f, -3e38f};   // running max, log2 domain
  float l[4] = {0.f, 0.f, 0.f, 0.f};
  float minm = -3e38f;
  const float Cs = 0.125f * 1.4426950408889634f;   // (1/sqrt(64)) * log2(e)
  const int xc = ((c & 7) << 4) ^ ((c & 8) << 2);

  auto loadK = [&](int kt, bf16x8 (&K)[4][2]) {
#pragma unroll
    for (int i = 0; i < 4; i++) {
      K[i][0] = *(const bf16x8*)(Kp + (size_t)(kt + i * 16 + c) * HDc + g * 8);
      K[i][1] = *(const bf16x8*)(Kp + (size_t)(kt + i * 16 + c) * HDc + 32 + g * 8);
    }
  };

  auto tile = [&](int kt, bf16x8 (&K)[4][2]) {
    f32x4 s[4];
#pragma unroll
    for (int i = 0; i < 4; i++) {
      s[i] = __builtin_amdgcn_mfma_f32_16x16x32_bf16(qf0, K[i][0], z, 0, 0, 0);
      s[i] = __builtin_amdgcn_mfma_f32_16x16x32_bf16(qf1, K[i][1], s[i], 0, 0, 0);
    }
    // issue V loads now: consumed only after softmax + P roundtrip (~400 cyc slack)
    bf16x8 v0[4], v1[4];
#pragma unroll
    for (int d4 = 0; d4 < 4; d4++) {
      v0[d4] = *(const bf16x8*)(Vp + (size_t)(d4 * 16 + c) * Tc + kt + g * 8);
      v1[d4] = *(const bf16x8*)(Vp + (size_t)(d4 * 16 + c) * Tc + kt + 32 + g * 8);
    }
#pragma unroll
    for (int i = 0; i < 4; i++)
#pragma unroll
      for (int r = 0; r < 4; r++) s[i][r] *= Cs;

    float LM = s[0][0];
#pragma unroll
    for (int i = 0; i < 4; i++)
#pragma unroll
      for (int r = 0; r < 4; r++) LM = fmaxf(LM, s[i][r]);

    if (!__all(LM <= minm + 8.0f)) {               // rare rescale path (T13)
#pragma unroll
      for (int r = 0; r < 4; r++) {
        float rm = fmaxf(fmaxf(s[0][r], s[1][r]), fmaxf(s[2][r], s[3][r]));
        rm = fmaxf(rm, __shfl_xor(rm, 1));
        rm = fmaxf(rm, __shfl_xor(rm, 2));
        rm = fmaxf(rm, __shfl_xor(rm, 4));
        rm = fmaxf(rm, __shfl_xor(rm, 8));
        float nm = fmaxf(m[r], rm);
        float ef = exp2f(m[r] - nm);
        m[r] = nm;
        l[r] *= ef;
        o[0][r] *= ef; o[1][r] *= ef; o[2][r] *= ef; o[3][r] *= ef;
      }
      minm = fminf(fminf(m[0], m[1]), fminf(m[2], m[3]));
    }

#pragma unroll
    for (int r = 0; r < 4; r++) {
      const int rw = g * 4 + r;
      const int xr = ((rw & 7) << 4) ^ ((rw & 8) << 2);
      float p0 = exp2f(s[0][r] - m[r]);
      float p1 = exp2f(s[1][r] - m[r]);
      float p2 = exp2f(s[2][r] - m[r]);
      float p3 = exp2f(s[3][r] - m[r]);
      l[r] += (p0 + p1) + (p2 + p3);
      *(unsigned short*)(Pw + rw * 128 + ((c * 2) ^ xr))      = f2bf(p0);
      *(unsigned short*)(Pw + rw * 128 + ((32 + c * 2) ^ xr)) = f2bf(p1);
      *(unsigned short*)(Pw + rw * 128 + ((64 + c * 2) ^ xr)) = f2bf(p2);
      *(unsigned short*)(Pw + rw * 128 + ((96 + c * 2) ^ xr)) = f2bf(p3);
    }

    const bf16x8 pf0 = *(const bf16x8*)(Pw + c * 128 + ((g * 16) ^ xc));
    const bf16x8 pf1 = *(const bf16x8*)(Pw + c * 128 + ((64 + g * 16) ^ xc));
#pragma unroll
    for (int d4 = 0; d4 < 4; d4++) {
      o[d4] = __builtin_amdgcn_mfma_f32_16x16x32_bf16(pf0, v0[d4], o[d4], 0, 0, 0);
      o[d4] = __builtin_amdgcn_mfma_f32_16x16x32_bf16(pf1, v1[d4], o[d4], 0, 0, 0);
    }
  };

  bf16x8 kA[4][2], kB[4][2];
  loadK(0, kA);
  for (int kt = 0; kt < Tc; kt += 128) {
    loadK(kt + 64, kB);
    tile(kt, kA);
    loadK((kt + 128) & (Tc - 1), kA);   // wraps to 0 on last iter (valid, unused)
    tile(kt + 64, kB);
  }

  float linv[4];
#pragma unroll
  for (int r = 0; r < 4; r++) {
    float L = l[r];
    L += __shfl_xor(L, 1); L += __shfl_xor(L, 2); L += __shfl_xor(L, 4); L += __shfl_xor(L, 8);
    linv[r] = 1.0f / L;
  }
  const int b = bh >> 4, h = bh & 15;
#pragma unroll
  for (int r = 0; r < 4; r++) {
    size_t rowoff = ((size_t)b * Tc + q0 + g * 4 + r) * Dc + h * HDc + c;
    Ob[rowoff + 0]  = f2bf(o[0][r] * linv[r]);
    Ob[rowoff + 16] = f2bf(o[1][r] * linv[r]);
    Ob[rowoff + 32] = f2bf(o[2][r] * linv[r]);
    Ob[rowoff + 48] = f2bf(o[3][r] * linv[r]);
  }
}

extern "C" void kernel_launch(void* const* d_in, const int* in_sizes, int n_in,
                              void* d_out, int out_size, void* d_ws, size_t ws_size,
                              hipStream_t stream) {
  const float* x     = (const float*)d_in[0];
  const float* w_qkv = (const float*)d_in[1];
  const float* w_out = (const float*)d_in[2];
  const float* w_ff1 = (const float*)d_in[3];
  const float* b_ff1 = (const float*)d_in[4];
  const float* w_ff2 = (const float*)d_in[5];
  const float* b_ff2 = (const float*)d_in[6];
  const float* g1    = (const float*)d_in[7];
  const float* be1   = (const float*)d_in[8];
  const float* g2    = (const float*)d_in[9];
  const float* be2   = (const float*)d_in[10];

  char* ws = (char*)d_ws;
  unsigned short* qkvb  = (unsigned short*)ws;                          // Q|K|V(row-major), 24 MB [0,24)
  unsigned short* xnvt  = (unsigned short*)(ws + ((size_t)24 << 20));   // xn (LN out) / Vt alias, 8 MB [24,32)
  unsigned short* Ob    = (unsigned short*)(ws + ((size_t)32 << 20));   // 8 MB  [32,40)
  unsigned short* hbuf  = (unsigned short*)(ws + ((size_t)40 << 20));   // 32 MB [40,72)
  unsigned short* wqkvT = (unsigned short*)(ws + ((size_t)72 << 20));   // 6 MB
  unsigned short* woutT = (unsigned short*)(ws + ((size_t)78 << 20));   // 2 MB
  unsigned short* wff1T = (unsigned short*)(ws + ((size_t)80 << 20));   // 8 MB
  unsigned short* wff2T = (unsigned short*)(ws + ((size_t)88 << 20));   // 8 MB -> 96 MB total
  float* x2 = (float*)d_out;   // fp32 residual scratch, overwritten by ff2 at the end

  dim3 blk(256);
  // weight transposes (fp32 -> bf16 [N][K])
  wconv_kernel<<<dim3(48, 16), blk, 0, stream>>>(w_qkv, wqkvT, Dc, 3 * Dc);
  wconv_kernel<<<dim3(16, 16), blk, 0, stream>>>(w_out, woutT, Dc, Dc);
  wconv_kernel<<<dim3(64, 16), blk, 0, stream>>>(w_ff1, wff1T, Dc, 4 * Dc);
  wconv_kernel<<<dim3(16, 64), blk, 0, stream>>>(w_ff2, wff2T, 4 * Dc, Dc);

  // xn = LN(x) in bf16   (xn lives in the xn/Vt alias region)
  ln_kernel<<<Mc, blk, 0, stream>>>(x, g1, be1, xnvt);
  // qkv GEMM with split Q/K/V bf16 epilogue
  gemm_bf16<<<dim3(24, 32), blk, 0, stream>>>(xnvt, wqkvT, nullptr, nullptr, nullptr, qkvb,
                                              Mc, 3 * Dc, Dc, 16);
  // V transpose into the (now dead) xn region
  vtrans<<<dim3(32, 32), blk, 0, stream>>>(qkvb + 8388608, xnvt);
  // flash attention
  fattn<<<dim3(1024), blk, 0, stream>>>(qkvb, qkvb + 4194304, xnvt, Ob);
  // x2 = x + attn @ w_out   (fp32 into d_out)
  gemm_bf16<<<dim3(8, 32), blk, 0, stream>>>(Ob, woutT, nullptr, x, x2, nullptr,
                                             Mc, Dc, Dc, 4);
  // xn = LN(x2) in bf16  (fattn done; region reusable)
  ln_kernel<<<Mc, blk, 0, stream>>>(x2, g2, be2, xnvt);
  // h = gelu(xn @ w_ff1 + b1) in bf16
  gemm_bf16<<<dim3(32, 32), blk, 0, stream>>>(xnvt, wff1T, b_ff1, nullptr, nullptr, hbuf,
                                              Mc, 4 * Dc, Dc, 1 | 2 | 8);
  // out = x2 + h @ w_ff2 + b2  (fp32)
  gemm_bf16<<<dim3(8, 32), blk, 0, stream>>>(hbuf, wff2T, b_ff2, x2, (float*)d_out, nullptr,
                                             Mc, Dc, 4 * Dc, 1 | 4);
}

// Round 8
// 523.931 us; speedup vs baseline: 1.2301x; 1.2301x over previous
//
#include <hip/hip_runtime.h>
#include <math.h>

#define Bc 2
#define Tc 2048
#define Dc 1024
#define Hc 16
#define HDc 64
#define Mc (Bc * Tc)   // 4096 rows

typedef __attribute__((ext_vector_type(4))) float f32x4;
typedef __attribute__((ext_vector_type(8))) short bf16x8;

__device__ __forceinline__ unsigned short f2bf(float f) {
  unsigned int u = __float_as_uint(f);
  u += 0x7fff + ((u >> 16) & 1);          // RNE
  return (unsigned short)(u >> 16);
}

__device__ __forceinline__ void gload16(const void* g, void* l) {
  __builtin_amdgcn_global_load_lds((const __attribute__((address_space(1))) unsigned int*)g,
                                   (__attribute__((address_space(3))) unsigned int*)l, 16, 0, 0);
}

// ---------- weight convert+transpose: W[K][N] f32 -> Wt[N][K] bf16 ----------
__global__ __launch_bounds__(256) void wconv_kernel(const float* __restrict__ W,
                                                    unsigned short* __restrict__ Wt,
                                                    int K, int N) {
  __shared__ float tile[64][65];
  const int t = threadIdx.x;
  const int kt = blockIdx.y * 64, nt = blockIdx.x * 64;
#pragma unroll
  for (int p = 0; p < 4; p++) {
    int kr = p * 16 + (t >> 4);
    int nc = (t & 15) * 4;
    float4 v = *(const float4*)&W[(size_t)(kt + kr) * N + nt + nc];
    tile[kr][nc] = v.x; tile[kr][nc + 1] = v.y; tile[kr][nc + 2] = v.z; tile[kr][nc + 3] = v.w;
  }
  __syncthreads();
  const int nr = t >> 2, kc = (t & 3) * 16;
  unsigned int u[8];
#pragma unroll
  for (int i = 0; i < 8; i++)
    u[i] = (unsigned int)f2bf(tile[kc + 2 * i][nr]) | ((unsigned int)f2bf(tile[kc + 2 * i + 1][nr]) << 16);
  uint4 w0; w0.x = u[0]; w0.y = u[1]; w0.z = u[2]; w0.w = u[3];
  uint4 w1; w1.x = u[4]; w1.y = u[5]; w1.z = u[6]; w1.w = u[7];
  *(uint4*)&Wt[(size_t)(nt + nr) * K + kt + kc] = w0;
  *(uint4*)&Wt[(size_t)(nt + nr) * K + kt + kc + 8] = w1;
}

// ---------- LayerNorm: fp32 in, bf16 out ----------
__global__ __launch_bounds__(256) void ln_kernel(const float* __restrict__ x,
                                                 const float* __restrict__ g,
                                                 const float* __restrict__ be,
                                                 unsigned short* __restrict__ out) {
  const int row = blockIdx.x;
  const int t = threadIdx.x;
  const float4* xp = (const float4*)(x + (size_t)row * Dc);
  float4 v = xp[t];
  float s = v.x + v.y + v.z + v.w;
  float s2 = v.x * v.x + v.y * v.y + v.z * v.z + v.w * v.w;
#pragma unroll
  for (int off = 32; off; off >>= 1) {
    s += __shfl_down(s, off);
    s2 += __shfl_down(s2, off);
  }
  __shared__ float rs[4], rs2[4];
  if ((t & 63) == 0) { rs[t >> 6] = s; rs2[t >> 6] = s2; }
  __syncthreads();
  float S = rs[0] + rs[1] + rs[2] + rs[3];
  float S2 = rs2[0] + rs2[1] + rs2[2] + rs2[3];
  float mean = S * (1.0f / Dc);
  float var = S2 * (1.0f / Dc) - mean * mean;
  float rstd = rsqrtf(var + 1e-5f);
  float4 gv = ((const float4*)g)[t];
  float4 bv = ((const float4*)be)[t];
  float o0 = (v.x - mean) * rstd * gv.x + bv.x;
  float o1 = (v.y - mean) * rstd * gv.y + bv.y;
  float o2 = (v.z - mean) * rstd * gv.z + bv.z;
  float o3 = (v.w - mean) * rstd * gv.w + bv.w;
  uint2 pk;
  pk.x = (unsigned int)f2bf(o0) | ((unsigned int)f2bf(o1) << 16);
  pk.y = (unsigned int)f2bf(o2) | ((unsigned int)f2bf(o3) << 16);
  *(uint2*)(out + (size_t)row * Dc + t * 4) = pk;
}

// ---------- bf16 MFMA GEMM: C[M,N] = A[M,K] @ Wt[N,K]^T, fused epilogue ----------
// flags: 1=+bias, 2=exact GELU, 4=+resid(fp32), 8=write bf16 to aux, 16=qkv split write
// qkv split layouts (all bf16, per bh = b*Hc+h, 131072 elems per bh per tensor):
//   Q : natural [bh][t][d]
//   KF: [bh][kg=t>>4][chunk=d>>3][c=t&15][8]   (fragment order -> lane-linear loads)
//   VF: [bh][kt=t>>6][d4=d>>4][h][g][c=d&15][8] with kk=t&63, h=kk>>5, g=(kk>>3)&3, j=kk&7
#define GBM 128
#define GBN 128
#define GBK 32

__global__ __launch_bounds__(256) void gemm_bf16(const unsigned short* __restrict__ A,
                                                 const unsigned short* __restrict__ Wt,
                                                 const float* __restrict__ bias,
                                                 const float* __restrict__ resid,
                                                 float* __restrict__ C,
                                                 unsigned short* __restrict__ aux,
                                                 int M, int N, int K, int flags) {
  __shared__ alignas(16) unsigned short As[GBM][GBK];   // 8 KB, row stride 64 B
  __shared__ alignas(16) unsigned short Bs[GBN][GBK];   // 8 KB (n-major)
  const int t = threadIdx.x;
  const int lane = t & 63, wave = t >> 6;
  const int wr = wave >> 1, wc = wave & 1;
  const int c = lane & 15, g = lane >> 4;
  const int row0 = blockIdx.y * GBM, col0 = blockIdx.x * GBN;

  f32x4 acc[4][4];
#pragma unroll
  for (int m = 0; m < 4; m++)
#pragma unroll
    for (int n = 0; n < 4; n++) acc[m][n] = (f32x4){0.f, 0.f, 0.f, 0.f};

  char* AsB = (char*)&As[0][0];
  char* BsB = (char*)&Bs[0][0];
  const int l0 = t, l1 = t + 256;
  const int lds0 = wave * 1024, lds1 = wave * 1024 + 4096;   // wave-uniform LDS bases

  for (int k0 = 0; k0 < K; k0 += GBK) {
    gload16(A + (size_t)(row0 + (l0 >> 2)) * K + k0 + (l0 & 3) * 8, AsB + lds0);
    gload16(A + (size_t)(row0 + (l1 >> 2)) * K + k0 + (l1 & 3) * 8, AsB + lds1);
    gload16(Wt + (size_t)(col0 + (l0 >> 2)) * K + k0 + (l0 & 3) * 8, BsB + lds0);
    gload16(Wt + (size_t)(col0 + (l1 >> 2)) * K + k0 + (l1 & 3) * 8, BsB + lds1);
    __syncthreads();
    bf16x8 af[4], bfv[4];
#pragma unroll
    for (int m = 0; m < 4; m++) af[m] = *(const bf16x8*)(AsB + (wr * 64 + m * 16 + c) * 64 + g * 16);
#pragma unroll
    for (int n = 0; n < 4; n++) bfv[n] = *(const bf16x8*)(BsB + (wc * 64 + n * 16 + c) * 64 + g * 16);
#pragma unroll
    for (int m = 0; m < 4; m++)
#pragma unroll
      for (int n = 0; n < 4; n++)
        acc[m][n] = __builtin_amdgcn_mfma_f32_16x16x32_bf16(af[m], bfv[n], acc[m][n], 0, 0, 0);
    __syncthreads();
  }

#pragma unroll
  for (int m = 0; m < 4; m++) {
    const int row = row0 + wr * 64 + m * 16 + g * 4;
#pragma unroll
    for (int n = 0; n < 4; n++) {
      const int col = col0 + wc * 64 + n * 16 + c;
      const float bi = (flags & 1) ? bias[col] : 0.0f;
#pragma unroll
      for (int r = 0; r < 4; r++) {
        float v = acc[m][n][r] + bi;
        if (flags & 2) v = 0.5f * v * (1.0f + erff(v * 0.70710678118654752f));
        if (flags & 4) v += resid[(size_t)(row + r) * N + col];
        if (flags & 16) {
          int rr = row + r;
          int b = rr >> 11, tt = rr & 2047;
          int s = col >> 10, wcol = col & 1023;
          int h = wcol >> 6, f = wcol & 63;
          size_t base = ((size_t)(b * Hc + h)) * 131072;
          unsigned short bv = f2bf(v);
          if (s == 0) {
            aux[base + (size_t)tt * HDc + f] = bv;                       // Q natural
          } else if (s == 1) {
            // KF fragment order
            aux[4194304 + base + (size_t)(tt >> 4) * 1024 + (f >> 3) * 128 + (tt & 15) * 8 + (f & 7)] = bv;
          } else {
            // VF fragment order
            int kk = tt & 63;
            aux[8388608 + base + (size_t)(tt >> 6) * 4096 + (f >> 4) * 1024 +
                ((kk >> 5) & 1) * 512 + ((kk >> 3) & 3) * 128 + (f & 15) * 8 + (kk & 7)] = bv;
          }
        } else if (flags & 8) {
          aux[(size_t)(row + r) * N + col] = f2bf(v);
        } else {
          C[(size_t)(row + r) * N + col] = v;
        }
      }
    }
  }
}

// ---------- MFMA flash attention v4: fragment-ordered K/V, lane-linear loads ----------
// Qb: [32 bh][2048][64] bf16 ; KF,VF: fragment order (see gemm epilogue) ; Ob: [B][T][D] bf16
__global__ __launch_bounds__(256, 4) void fattn(const unsigned short* __restrict__ Qb,
                                                const unsigned short* __restrict__ KF,
                                                const unsigned short* __restrict__ VF,
                                                unsigned short* __restrict__ Ob) {
  __shared__ alignas(16) unsigned short P[4][16][64];   // 8 KB, 128 B rows, XOR-swizzled
  const int t = threadIdx.x, wave = t >> 6, lane = t & 63;
  const int c = lane & 15, g = lane >> 4;
  const int bid = blockIdx.x;
  // XCD-aware: bid%8 selects a group of 4 bh -> each XCD's L2 holds only 4 bh of K/V
  const int bh = ((bid & 7) << 2) | ((bid >> 3) & 3);
  const int qt = bid >> 5;
  const int q0 = qt * 64 + wave * 16;

  const unsigned short* Qp = Qb + ((size_t)bh * Tc + q0) * HDc;
  const unsigned short* Kp = KF + (size_t)bh * 131072;   // [kg][chunk][c][8]
  const unsigned short* Vp = VF + (size_t)bh * 131072;   // [ktile][d4][h][g][c][8]
  char* Pw = (char*)&P[wave][0][0];

  const bf16x8 qf0 = *(const bf16x8*)(Qp + c * HDc + g * 8);
  const bf16x8 qf1 = *(const bf16x8*)(Qp + c * HDc + 32 + g * 8);

  const f32x4 z = {0.f, 0.f, 0.f, 0.f};
  f32x4 o[4] = {z, z, z, z};
  float m[4] = {-3e38f, -3e38f, -3e38f, -3e38f};   // running max, log2 domain
  float l[4] = {0.f, 0.f, 0.f, 0.f};
  float minm = -3e38f;
  const float Cs = 0.125f * 1.4426950408889634f;   // (1/sqrt(64)) * log2(e)
  const int xc = ((c & 7) << 4) ^ ((c & 8) << 2);
  const int lofs = lane * 8;                        // (g*16+c)*8 == lane*8: lane-linear

  auto loadK = [&](int kt, bf16x8 (&K)[4][2]) {
    const unsigned short* kb = Kp + (kt >> 4) * 1024 + lofs;
#pragma unroll
    for (int i = 0; i < 4; i++) {
      K[i][0] = *(const bf16x8*)(kb + i * 1024);          // chunks 0..3 (d 0..31)
      K[i][1] = *(const bf16x8*)(kb + i * 1024 + 512);    // chunks 4..7 (d 32..63)
    }
  };

  auto tile = [&](int kt, bf16x8 (&K)[4][2]) {
    f32x4 s[4];
#pragma unroll
    for (int i = 0; i < 4; i++) {
      s[i] = __builtin_amdgcn_mfma_f32_16x16x32_bf16(qf0, K[i][0], z, 0, 0, 0);
      s[i] = __builtin_amdgcn_mfma_f32_16x16x32_bf16(qf1, K[i][1], s[i], 0, 0, 0);
    }
    // issue V loads now: consumed only after softmax + P roundtrip (~400 cyc slack)
    const unsigned short* vb = Vp + (kt >> 6) * 4096 + lofs;
    bf16x8 v0[4], v1[4];
#pragma unroll
    for (int d4 = 0; d4 < 4; d4++) {
      v0[d4] = *(const bf16x8*)(vb + d4 * 1024);          // h=0 (keys kt..kt+31)
      v1[d4] = *(const bf16x8*)(vb + d4 * 1024 + 512);    // h=1 (keys kt+32..kt+63)
    }
#pragma unroll
    for (int i = 0; i < 4; i++)
#pragma unroll
      for (int r = 0; r < 4; r++) s[i][r] *= Cs;

    float LM = s[0][0];
#pragma unroll
    for (int i = 0; i < 4; i++)
#pragma unroll
      for (int r = 0; r < 4; r++) LM = fmaxf(LM, s[i][r]);

    if (!__all(LM <= minm + 8.0f)) {               // rare rescale path (T13)
#pragma unroll
      for (int r = 0; r < 4; r++) {
        float rm = fmaxf(fmaxf(s[0][r], s[1][r]), fmaxf(s[2][r], s[3][r]));
        rm = fmaxf(rm, __shfl_xor(rm, 1));
        rm = fmaxf(rm, __shfl_xor(rm, 2));
        rm = fmaxf(rm, __shfl_xor(rm, 4));
        rm = fmaxf(rm, __shfl_xor(rm, 8));
        float nm = fmaxf(m[r], rm);
        float ef = exp2f(m[r] - nm);
        m[r] = nm;
        l[r] *= ef;
        o[0][r] *= ef; o[1][r] *= ef; o[2][r] *= ef; o[3][r] *= ef;
      }
      minm = fminf(fminf(m[0], m[1]), fminf(m[2], m[3]));
    }

#pragma unroll
    for (int r = 0; r < 4; r++) {
      const int rw = g * 4 + r;
      const int xr = ((rw & 7) << 4) ^ ((rw & 8) << 2);
      float p0 = exp2f(s[0][r] - m[r]);
      float p1 = exp2f(s[1][r] - m[r]);
      float p2 = exp2f(s[2][r] - m[r]);
      float p3 = exp2f(s[3][r] - m[r]);
      l[r] += (p0 + p1) + (p2 + p3);
      *(unsigned short*)(Pw + rw * 128 + ((c * 2) ^ xr))      = f2bf(p0);
      *(unsigned short*)(Pw + rw * 128 + ((32 + c * 2) ^ xr)) = f2bf(p1);
      *(unsigned short*)(Pw + rw * 128 + ((64 + c * 2) ^ xr)) = f2bf(p2);
      *(unsigned short*)(Pw + rw * 128 + ((96 + c * 2) ^ xr)) = f2bf(p3);
    }

    const bf16x8 pf0 = *(const bf16x8*)(Pw + c * 128 + ((g * 16) ^ xc));
    const bf16x8 pf1 = *(const bf16x8*)(Pw + c * 128 + ((64 + g * 16) ^ xc));
#pragma unroll
    for (int d4 = 0; d4 < 4; d4++) {
      o[d4] = __builtin_amdgcn_mfma_f32_16x16x32_bf16(pf0, v0[d4], o[d4], 0, 0, 0);
      o[d4] = __builtin_amdgcn_mfma_f32_16x16x32_bf16(pf1, v1[d4], o[d4], 0, 0, 0);
    }
  };

  bf16x8 kA[4][2], kB[4][2];
  loadK(0, kA);
  for (int kt = 0; kt < Tc; kt += 128) {
    loadK(kt + 64, kB);
    tile(kt, kA);
    loadK((kt + 128) & (Tc - 1), kA);   // wraps to 0 on last iter (valid, unused)
    tile(kt + 64, kB);
  }

  float linv[4];
#pragma unroll
  for (int r = 0; r < 4; r++) {
    float L = l[r];
    L += __shfl_xor(L, 1); L += __shfl_xor(L, 2); L += __shfl_xor(L, 4); L += __shfl_xor(L, 8);
    linv[r] = 1.0f / L;
  }
  const int b = bh >> 4, h = bh & 15;
#pragma unroll
  for (int r = 0; r < 4; r++) {
    size_t rowoff = ((size_t)b * Tc + q0 + g * 4 + r) * Dc + h * HDc + c;
    Ob[rowoff + 0]  = f2bf(o[0][r] * linv[r]);
    Ob[rowoff + 16] = f2bf(o[1][r] * linv[r]);
    Ob[rowoff + 32] = f2bf(o[2][r] * linv[r]);
    Ob[rowoff + 48] = f2bf(o[3][r] * linv[r]);
  }
}

extern "C" void kernel_launch(void* const* d_in, const int* in_sizes, int n_in,
                              void* d_out, int out_size, void* d_ws, size_t ws_size,
                              hipStream_t stream) {
  const float* x     = (const float*)d_in[0];
  const float* w_qkv = (const float*)d_in[1];
  const float* w_out = (const float*)d_in[2];
  const float* w_ff1 = (const float*)d_in[3];
  const float* b_ff1 = (const float*)d_in[4];
  const float* w_ff2 = (const float*)d_in[5];
  const float* b_ff2 = (const float*)d_in[6];
  const float* g1    = (const float*)d_in[7];
  const float* be1   = (const float*)d_in[8];
  const float* g2    = (const float*)d_in[9];
  const float* be2   = (const float*)d_in[10];

  char* ws = (char*)d_ws;
  unsigned short* qkvb  = (unsigned short*)ws;                          // Q|KF|VF bf16, 24 MB [0,24)
  unsigned short* xn    = (unsigned short*)(ws + ((size_t)24 << 20));   // 8 MB  [24,32)
  unsigned short* Ob    = (unsigned short*)(ws + ((size_t)32 << 20));   // 8 MB  [32,40)
  unsigned short* hbuf  = (unsigned short*)(ws + ((size_t)40 << 20));   // 32 MB [40,72)
  unsigned short* wqkvT = (unsigned short*)(ws + ((size_t)72 << 20));   // 6 MB
  unsigned short* woutT = (unsigned short*)(ws + ((size_t)78 << 20));   // 2 MB
  unsigned short* wff1T = (unsigned short*)(ws + ((size_t)80 << 20));   // 8 MB
  unsigned short* wff2T = (unsigned short*)(ws + ((size_t)88 << 20));   // 8 MB -> 96 MB total
  float* x2 = (float*)d_out;   // fp32 residual scratch, overwritten by ff2 at the end

  dim3 blk(256);
  // weight transposes (fp32 -> bf16 [N][K])
  wconv_kernel<<<dim3(48, 16), blk, 0, stream>>>(w_qkv, wqkvT, Dc, 3 * Dc);
  wconv_kernel<<<dim3(16, 16), blk, 0, stream>>>(w_out, woutT, Dc, Dc);
  wconv_kernel<<<dim3(64, 16), blk, 0, stream>>>(w_ff1, wff1T, Dc, 4 * Dc);
  wconv_kernel<<<dim3(16, 64), blk, 0, stream>>>(w_ff2, wff2T, 4 * Dc, Dc);

  // xn = LN(x) in bf16
  ln_kernel<<<Mc, blk, 0, stream>>>(x, g1, be1, xn);
  // qkv GEMM with fragment-ordered Q/KF/VF epilogue (no vtrans needed)
  gemm_bf16<<<dim3(24, 32), blk, 0, stream>>>(xn, wqkvT, nullptr, nullptr, nullptr, qkvb,
                                              Mc, 3 * Dc, Dc, 16);
  // flash attention
  fattn<<<dim3(1024), blk, 0, stream>>>(qkvb, qkvb + 4194304, qkvb + 8388608, Ob);
  // x2 = x + attn @ w_out   (fp32 into d_out)
  gemm_bf16<<<dim3(8, 32), blk, 0, stream>>>(Ob, woutT, nullptr, x, x2, nullptr,
                                             Mc, Dc, Dc, 4);
  // xn = LN(x2) in bf16
  ln_kernel<<<Mc, blk, 0, stream>>>(x2, g2, be2, xn);
  // h = gelu(xn @ w_ff1 + b1) in bf16
  gemm_bf16<<<dim3(32, 32), blk, 0, stream>>>(xn, wff1T, b_ff1, nullptr, nullptr, hbuf,
                                              Mc, 4 * Dc, Dc, 1 | 2 | 8);
  // out = x2 + h @ w_ff2 + b2  (fp32)
  gemm_bf16<<<dim3(8, 32), blk, 0, stream>>>(hbuf, wff2T, b_ff2, x2, (float*)d_out, nullptr,
                                             Mc, Dc, 4 * Dc, 1 | 4);
}

// Round 9
// 457.439 us; speedup vs baseline: 1.4089x; 1.1454x over previous
//
#include <hip/hip_runtime.h>
#include <math.h>

#define Bc 2
#define Tc 2048
#define Dc 1024
#define Hc 16
#define HDc 64
#define Mc (Bc * Tc)   // 4096 rows

typedef __attribute__((ext_vector_type(4))) float f32x4;
typedef __attribute__((ext_vector_type(8))) short bf16x8;

__device__ __forceinline__ unsigned short f2bf(float f) {
  unsigned int u = __float_as_uint(f);
  u += 0x7fff + ((u >> 16) & 1);          // RNE
  return (unsigned short)(u >> 16);
}

__device__ __forceinline__ void gload16(const void* g, void* l) {
  __builtin_amdgcn_global_load_lds((const __attribute__((address_space(1))) unsigned int*)g,
                                   (__attribute__((address_space(3))) unsigned int*)l, 16, 0, 0);
}

// ---------- fused weight convert+transpose: all four W[K][N] f32 -> Wt[N][K] bf16 ----------
__global__ __launch_bounds__(256) void wconv_all(const float* __restrict__ w0, const float* __restrict__ w1,
                                                 const float* __restrict__ w2, const float* __restrict__ w3,
                                                 unsigned short* __restrict__ o0, unsigned short* __restrict__ o1,
                                                 unsigned short* __restrict__ o2, unsigned short* __restrict__ o3) {
  __shared__ float tile[64][65];
  int bid = blockIdx.x;
  const float* W; unsigned short* Wt; int K, N, tx;
  if (bid < 768)       { W = w0; Wt = o0; K = 1024; N = 3072; tx = 48; }
  else if (bid < 1024) { bid -= 768;  W = w1; Wt = o1; K = 1024; N = 1024; tx = 16; }
  else if (bid < 2048) { bid -= 1024; W = w2; Wt = o2; K = 1024; N = 4096; tx = 64; }
  else                 { bid -= 2048; W = w3; Wt = o3; K = 4096; N = 1024; tx = 16; }
  const int kt = (bid / tx) * 64, nt = (bid % tx) * 64;
  const int t = threadIdx.x;
#pragma unroll
  for (int p = 0; p < 4; p++) {
    int kr = p * 16 + (t >> 4);
    int nc = (t & 15) * 4;
    float4 v = *(const float4*)&W[(size_t)(kt + kr) * N + nt + nc];
    tile[kr][nc] = v.x; tile[kr][nc + 1] = v.y; tile[kr][nc + 2] = v.z; tile[kr][nc + 3] = v.w;
  }
  __syncthreads();
  const int nr = t >> 2, kc = (t & 3) * 16;
  unsigned int u[8];
#pragma unroll
  for (int i = 0; i < 8; i++)
    u[i] = (unsigned int)f2bf(tile[kc + 2 * i][nr]) | ((unsigned int)f2bf(tile[kc + 2 * i + 1][nr]) << 16);
  uint4 q0; q0.x = u[0]; q0.y = u[1]; q0.z = u[2]; q0.w = u[3];
  uint4 q1; q1.x = u[4]; q1.y = u[5]; q1.z = u[6]; q1.w = u[7];
  *(uint4*)&Wt[(size_t)(nt + nr) * K + kt + kc] = q0;
  *(uint4*)&Wt[(size_t)(nt + nr) * K + kt + kc + 8] = q1;
}

// ---------- LayerNorm: fp32 in, bf16 out ----------
__global__ __launch_bounds__(256) void ln_kernel(const float* __restrict__ x,
                                                 const float* __restrict__ g,
                                                 const float* __restrict__ be,
                                                 unsigned short* __restrict__ out) {
  const int row = blockIdx.x;
  const int t = threadIdx.x;
  const float4* xp = (const float4*)(x + (size_t)row * Dc);
  float4 v = xp[t];
  float s = v.x + v.y + v.z + v.w;
  float s2 = v.x * v.x + v.y * v.y + v.z * v.z + v.w * v.w;
#pragma unroll
  for (int off = 32; off; off >>= 1) {
    s += __shfl_down(s, off);
    s2 += __shfl_down(s2, off);
  }
  __shared__ float rs[4], rs2[4];
  if ((t & 63) == 0) { rs[t >> 6] = s; rs2[t >> 6] = s2; }
  __syncthreads();
  float S = rs[0] + rs[1] + rs[2] + rs[3];
  float S2 = rs2[0] + rs2[1] + rs2[2] + rs2[3];
  float mean = S * (1.0f / Dc);
  float var = S2 * (1.0f / Dc) - mean * mean;
  float rstd = rsqrtf(var + 1e-5f);
  float4 gv = ((const float4*)g)[t];
  float4 bv = ((const float4*)be)[t];
  float o0 = (v.x - mean) * rstd * gv.x + bv.x;
  float o1 = (v.y - mean) * rstd * gv.y + bv.y;
  float o2 = (v.z - mean) * rstd * gv.z + bv.z;
  float o3 = (v.w - mean) * rstd * gv.w + bv.w;
  uint2 pk;
  pk.x = (unsigned int)f2bf(o0) | ((unsigned int)f2bf(o1) << 16);
  pk.y = (unsigned int)f2bf(o2) | ((unsigned int)f2bf(o3) << 16);
  *(uint2*)(out + (size_t)row * Dc + t * 4) = pk;
}

// ---------- bf16 MFMA GEMM, templated BM (128 or 64), BN=128 ----------
// dbuf LDS, one barrier/K-step, stage-after-barrier overlap, XCD column-stripe remap.
// flags: 1=+bias, 2=exact GELU, 4=+resid(fp32), 8=write bf16 to aux, 16=qkv split write
// qkv split layouts (all bf16, per bh = b*Hc+h, 131072 elems per bh per tensor):
//   Q : natural [bh][t][d]
//   KF: [bh][kg=t>>4][chunk=d>>3][c=t&15][8]
//   VF: [bh][kt=t>>6][d4=d>>4][h][g][c=d&15][8] with kk=t&63, h=kk>>5, g=(kk>>3)&3
template<int BM>
__global__ __launch_bounds__(256) void gemm_bf16(const unsigned short* __restrict__ A,
                                                 const unsigned short* __restrict__ Wt,
                                                 const float* __restrict__ bias,
                                                 const float* __restrict__ resid,
                                                 float* __restrict__ C,
                                                 unsigned short* __restrict__ aux,
                                                 int M, int N, int K, int flags) {
  constexpr int BN = 128;
  constexpr int NW = (BM == 128) ? 2 : 4;   // waves along N
  constexpr int WN = BN / NW;               // 64 or 32 cols per wave
  constexpr int NFR = WN / 16;              // 4 or 2 col-frags
  constexpr int ALOADS = BM / 64;           // staging iterations for A
  __shared__ alignas(16) unsigned short As[2][BM][32];
  __shared__ alignas(16) unsigned short Bs[2][BN][32];
  const int t = threadIdx.x;
  const int lane = t & 63, wave = t >> 6;
  const int wr = (BM == 128) ? (wave >> 1) : 0;
  const int wc = (BM == 128) ? (wave & 1) : wave;
  const int c = lane & 15, g = lane >> 4;

  // XCD column-stripe remap (bijective; all grids have nwg % 8 == 0, gx % 8 == 0 or sw>=1)
  const int gx = N / BN;
  const int sw = gx >> 3;                   // x-stripe width per XCD
  const int bid = blockIdx.x;
  const int xcd = bid & 7, lid = bid >> 3;
  const int lx = xcd * sw + lid % sw;
  const int ly = lid / sw;
  const int row0 = ly * BM, col0 = lx * BN;

  f32x4 acc[4][NFR];
#pragma unroll
  for (int m = 0; m < 4; m++)
#pragma unroll
    for (int n = 0; n < NFR; n++) acc[m][n] = (f32x4){0.f, 0.f, 0.f, 0.f};

  auto stage = [&](int k0, int buf) {
    char* AsB = (char*)&As[buf][0][0] + wave * 1024;
    char* BsB = (char*)&Bs[buf][0][0] + wave * 1024;
#pragma unroll
    for (int i = 0; i < ALOADS; i++) {
      int l = t + 256 * i;
      gload16(A + (size_t)(row0 + (l >> 2)) * K + k0 + (l & 3) * 8, AsB + i * 4096);
    }
#pragma unroll
    for (int i = 0; i < 2; i++) {
      int l = t + 256 * i;
      gload16(Wt + (size_t)(col0 + (l >> 2)) * K + k0 + (l & 3) * 8, BsB + i * 4096);
    }
  };

  const int nk = K / 32;
  stage(0, 0);
  for (int ki = 0; ki < nk; ki++) {
    const int buf = ki & 1;
    __syncthreads();                          // stage(ki) complete; buf readable
    if (ki + 1 < nk) stage((ki + 1) * 32, buf ^ 1);   // in flight under compute
    const char* Ab = (const char*)&As[buf][0][0];
    const char* Bb = (const char*)&Bs[buf][0][0];
    bf16x8 af[4], bfv[NFR];
#pragma unroll
    for (int m = 0; m < 4; m++) af[m] = *(const bf16x8*)(Ab + (wr * 64 + m * 16 + c) * 64 + g * 16);
#pragma unroll
    for (int n = 0; n < NFR; n++) bfv[n] = *(const bf16x8*)(Bb + (wc * WN + n * 16 + c) * 64 + g * 16);
#pragma unroll
    for (int m = 0; m < 4; m++)
#pragma unroll
      for (int n = 0; n < NFR; n++)
        acc[m][n] = __builtin_amdgcn_mfma_f32_16x16x32_bf16(af[m], bfv[n], acc[m][n], 0, 0, 0);
  }

#pragma unroll
  for (int m = 0; m < 4; m++) {
    const int row = row0 + wr * 64 + m * 16 + g * 4;
#pragma unroll
    for (int n = 0; n < NFR; n++) {
      const int col = col0 + wc * WN + n * 16 + c;
      const float bi = (flags & 1) ? bias[col] : 0.0f;
#pragma unroll
      for (int r = 0; r < 4; r++) {
        float v = acc[m][n][r] + bi;
        if (flags & 2) v = 0.5f * v * (1.0f + erff(v * 0.70710678118654752f));
        if (flags & 4) v += resid[(size_t)(row + r) * N + col];
        if (flags & 16) {
          int rr = row + r;
          int b = rr >> 11, tt = rr & 2047;
          int s = col >> 10, wcol = col & 1023;
          int h = wcol >> 6, f = wcol & 63;
          size_t base = ((size_t)(b * Hc + h)) * 131072;
          unsigned short bv = f2bf(v);
          if (s == 0) {
            aux[base + (size_t)tt * HDc + f] = bv;                       // Q natural
          } else if (s == 1) {
            aux[4194304 + base + (size_t)(tt >> 4) * 1024 + (f >> 3) * 128 + (tt & 15) * 8 + (f & 7)] = bv;
          } else {
            int kk = tt & 63;
            aux[8388608 + base + (size_t)(tt >> 6) * 4096 + (f >> 4) * 1024 +
                ((kk >> 5) & 1) * 512 + ((kk >> 3) & 3) * 128 + (f & 15) * 8 + (kk & 7)] = bv;
          }
        } else if (flags & 8) {
          aux[(size_t)(row + r) * N + col] = f2bf(v);
        } else {
          C[(size_t)(row + r) * N + col] = v;
        }
      }
    }
  }
}

// ---------- MFMA flash attention v4: fragment-ordered K/V, lane-linear loads ----------
__global__ __launch_bounds__(256, 4) void fattn(const unsigned short* __restrict__ Qb,
                                                const unsigned short* __restrict__ KF,
                                                const unsigned short* __restrict__ VF,
                                                unsigned short* __restrict__ Ob) {
  __shared__ alignas(16) unsigned short P[4][16][64];   // 8 KB, 128 B rows, XOR-swizzled
  const int t = threadIdx.x, wave = t >> 6, lane = t & 63;
  const int c = lane & 15, g = lane >> 4;
  const int bid = blockIdx.x;
  const int bh = ((bid & 7) << 2) | ((bid >> 3) & 3);
  const int qt = bid >> 5;
  const int q0 = qt * 64 + wave * 16;

  const unsigned short* Qp = Qb + ((size_t)bh * Tc + q0) * HDc;
  const unsigned short* Kp = KF + (size_t)bh * 131072;   // [kg][chunk][c][8]
  const unsigned short* Vp = VF + (size_t)bh * 131072;   // [ktile][d4][h][g][c][8]
  char* Pw = (char*)&P[wave][0][0];

  const bf16x8 qf0 = *(const bf16x8*)(Qp + c * HDc + g * 8);
  const bf16x8 qf1 = *(const bf16x8*)(Qp + c * HDc + 32 + g * 8);

  const f32x4 z = {0.f, 0.f, 0.f, 0.f};
  f32x4 o[4] = {z, z, z, z};
  float m[4] = {-3e38f, -3e38f, -3e38f, -3e38f};
  float l[4] = {0.f, 0.f, 0.f, 0.f};
  float minm = -3e38f;
  const float Cs = 0.125f * 1.4426950408889634f;
  const int xc = ((c & 7) << 4) ^ ((c & 8) << 2);
  const int lofs = lane * 8;

  auto loadK = [&](int kt, bf16x8 (&K)[4][2]) {
    const unsigned short* kb = Kp + (kt >> 4) * 1024 + lofs;
#pragma unroll
    for (int i = 0; i < 4; i++) {
      K[i][0] = *(const bf16x8*)(kb + i * 1024);
      K[i][1] = *(const bf16x8*)(kb + i * 1024 + 512);
    }
  };

  auto tile = [&](int kt, bf16x8 (&K)[4][2]) {
    f32x4 s[4];
#pragma unroll
    for (int i = 0; i < 4; i++) {
      s[i] = __builtin_amdgcn_mfma_f32_16x16x32_bf16(qf0, K[i][0], z, 0, 0, 0);
      s[i] = __builtin_amdgcn_mfma_f32_16x16x32_bf16(qf1, K[i][1], s[i], 0, 0, 0);
    }
    const unsigned short* vb = Vp + (kt >> 6) * 4096 + lofs;
    bf16x8 v0[4], v1[4];
#pragma unroll
    for (int d4 = 0; d4 < 4; d4++) {
      v0[d4] = *(const bf16x8*)(vb + d4 * 1024);
      v1[d4] = *(const bf16x8*)(vb + d4 * 1024 + 512);
    }
#pragma unroll
    for (int i = 0; i < 4; i++)
#pragma unroll
      for (int r = 0; r < 4; r++) s[i][r] *= Cs;

    float LM = s[0][0];
#pragma unroll
    for (int i = 0; i < 4; i++)
#pragma unroll
      for (int r = 0; r < 4; r++) LM = fmaxf(LM, s[i][r]);

    if (!__all(LM <= minm + 8.0f)) {               // rare rescale path (T13)
#pragma unroll
      for (int r = 0; r < 4; r++) {
        float rm = fmaxf(fmaxf(s[0][r], s[1][r]), fmaxf(s[2][r], s[3][r]));
        rm = fmaxf(rm, __shfl_xor(rm, 1));
        rm = fmaxf(rm, __shfl_xor(rm, 2));
        rm = fmaxf(rm, __shfl_xor(rm, 4));
        rm = fmaxf(rm, __shfl_xor(rm, 8));
        float nm = fmaxf(m[r], rm);
        float ef = exp2f(m[r] - nm);
        m[r] = nm;
        l[r] *= ef;
        o[0][r] *= ef; o[1][r] *= ef; o[2][r] *= ef; o[3][r] *= ef;
      }
      minm = fminf(fminf(m[0], m[1]), fminf(m[2], m[3]));
    }

#pragma unroll
    for (int r = 0; r < 4; r++) {
      const int rw = g * 4 + r;
      const int xr = ((rw & 7) << 4) ^ ((rw & 8) << 2);
      float p0 = exp2f(s[0][r] - m[r]);
      float p1 = exp2f(s[1][r] - m[r]);
      float p2 = exp2f(s[2][r] - m[r]);
      float p3 = exp2f(s[3][r] - m[r]);
      l[r] += (p0 + p1) + (p2 + p3);
      *(unsigned short*)(Pw + rw * 128 + ((c * 2) ^ xr))      = f2bf(p0);
      *(unsigned short*)(Pw + rw * 128 + ((32 + c * 2) ^ xr)) = f2bf(p1);
      *(unsigned short*)(Pw + rw * 128 + ((64 + c * 2) ^ xr)) = f2bf(p2);
      *(unsigned short*)(Pw + rw * 128 + ((96 + c * 2) ^ xr)) = f2bf(p3);
    }

    const bf16x8 pf0 = *(const bf16x8*)(Pw + c * 128 + ((g * 16) ^ xc));
    const bf16x8 pf1 = *(const bf16x8*)(Pw + c * 128 + ((64 + g * 16) ^ xc));
#pragma unroll
    for (int d4 = 0; d4 < 4; d4++) {
      o[d4] = __builtin_amdgcn_mfma_f32_16x16x32_bf16(pf0, v0[d4], o[d4], 0, 0, 0);
      o[d4] = __builtin_amdgcn_mfma_f32_16x16x32_bf16(pf1, v1[d4], o[d4], 0, 0, 0);
    }
  };

  bf16x8 kA[4][2], kB[4][2];
  loadK(0, kA);
  for (int kt = 0; kt < Tc; kt += 128) {
    loadK(kt + 64, kB);
    tile(kt, kA);
    loadK((kt + 128) & (Tc - 1), kA);
    tile(kt + 64, kB);
  }

  float linv[4];
#pragma unroll
  for (int r = 0; r < 4; r++) {
    float L = l[r];
    L += __shfl_xor(L, 1); L += __shfl_xor(L, 2); L += __shfl_xor(L, 4); L += __shfl_xor(L, 8);
    linv[r] = 1.0f / L;
  }
  const int b = bh >> 4, h = bh & 15;
#pragma unroll
  for (int r = 0; r < 4; r++) {
    size_t rowoff = ((size_t)b * Tc + q0 + g * 4 + r) * Dc + h * HDc + c;
    Ob[rowoff + 0]  = f2bf(o[0][r] * linv[r]);
    Ob[rowoff + 16] = f2bf(o[1][r] * linv[r]);
    Ob[rowoff + 32] = f2bf(o[2][r] * linv[r]);
    Ob[rowoff + 48] = f2bf(o[3][r] * linv[r]);
  }
}

extern "C" void kernel_launch(void* const* d_in, const int* in_sizes, int n_in,
                              void* d_out, int out_size, void* d_ws, size_t ws_size,
                              hipStream_t stream) {
  const float* x     = (const float*)d_in[0];
  const float* w_qkv = (const float*)d_in[1];
  const float* w_out = (const float*)d_in[2];
  const float* w_ff1 = (const float*)d_in[3];
  const float* b_ff1 = (const float*)d_in[4];
  const float* w_ff2 = (const float*)d_in[5];
  const float* b_ff2 = (const float*)d_in[6];
  const float* g1    = (const float*)d_in[7];
  const float* be1   = (const float*)d_in[8];
  const float* g2    = (const float*)d_in[9];
  const float* be2   = (const float*)d_in[10];

  char* ws = (char*)d_ws;
  unsigned short* qkvb  = (unsigned short*)ws;                          // Q|KF|VF bf16, 24 MB [0,24)
  unsigned short* xn    = (unsigned short*)(ws + ((size_t)24 << 20));   // 8 MB  [24,32)
  unsigned short* Ob    = (unsigned short*)(ws + ((size_t)32 << 20));   // 8 MB  [32,40)
  unsigned short* hbuf  = (unsigned short*)(ws + ((size_t)40 << 20));   // 32 MB [40,72)
  unsigned short* wqkvT = (unsigned short*)(ws + ((size_t)72 << 20));   // 6 MB
  unsigned short* woutT = (unsigned short*)(ws + ((size_t)78 << 20));   // 2 MB
  unsigned short* wff1T = (unsigned short*)(ws + ((size_t)80 << 20));   // 8 MB
  unsigned short* wff2T = (unsigned short*)(ws + ((size_t)88 << 20));   // 8 MB -> 96 MB total
  float* x2 = (float*)d_out;   // fp32 residual scratch, overwritten by ff2 at the end

  dim3 blk(256);
  // all four weight transposes in one launch
  wconv_all<<<3072, blk, 0, stream>>>(w_qkv, w_out, w_ff1, w_ff2, wqkvT, woutT, wff1T, wff2T);

  // xn = LN(x) in bf16
  ln_kernel<<<Mc, blk, 0, stream>>>(x, g1, be1, xn);
  // qkv GEMM with fragment-ordered Q/KF/VF epilogue
  gemm_bf16<128><<<768, blk, 0, stream>>>(xn, wqkvT, nullptr, nullptr, nullptr, qkvb,
                                          Mc, 3 * Dc, Dc, 16);
  // flash attention
  fattn<<<dim3(1024), blk, 0, stream>>>(qkvb, qkvb + 4194304, qkvb + 8388608, Ob);
  // x2 = x + attn @ w_out   (fp32 into d_out); BM=64 -> 512 blocks
  gemm_bf16<64><<<512, blk, 0, stream>>>(Ob, woutT, nullptr, x, x2, nullptr,
                                         Mc, Dc, Dc, 4);
  // xn = LN(x2) in bf16
  ln_kernel<<<Mc, blk, 0, stream>>>(x2, g2, be2, xn);
  // h = gelu(xn @ w_ff1 + b1) in bf16
  gemm_bf16<128><<<1024, blk, 0, stream>>>(xn, wff1T, b_ff1, nullptr, nullptr, hbuf,
                                           Mc, 4 * Dc, Dc, 1 | 2 | 8);
  // out = x2 + h @ w_ff2 + b2  (fp32); BM=64 -> 512 blocks
  gemm_bf16<64><<<512, blk, 0, stream>>>(hbuf, wff2T, b_ff2, x2, (float*)d_out, nullptr,
                                         Mc, Dc, 4 * Dc, 1 | 4);
}

// Round 10
// 435.887 us; speedup vs baseline: 1.4786x; 1.0494x over previous
//
#include <hip/hip_runtime.h>
#include <math.h>

#define Bc 2
#define Tc 2048
#define Dc 1024
#define Hc 16
#define HDc 64
#define Mc (Bc * Tc)   // 4096 rows

typedef __attribute__((ext_vector_type(4))) float f32x4;
typedef __attribute__((ext_vector_type(8))) short bf16x8;

__device__ __forceinline__ unsigned short f2bf(float f) {
  unsigned int u = __float_as_uint(f);
  u += 0x7fff + ((u >> 16) & 1);          // RNE
  return (unsigned short)(u >> 16);
}

__device__ __forceinline__ unsigned int cvtpk(float lo, float hi) {
  unsigned int r;
  asm("v_cvt_pk_bf16_f32 %0, %1, %2" : "=v"(r) : "v"(lo), "v"(hi));
  return r;
}

__device__ __forceinline__ void gload16(const void* g, void* l) {
  __builtin_amdgcn_global_load_lds((const __attribute__((address_space(1))) unsigned int*)g,
                                   (__attribute__((address_space(3))) unsigned int*)l, 16, 0, 0);
}

// ---------- fused weight convert+transpose: all four W[K][N] f32 -> Wt[N][K] bf16 ----------
__global__ __launch_bounds__(256) void wconv_all(const float* __restrict__ w0, const float* __restrict__ w1,
                                                 const float* __restrict__ w2, const float* __restrict__ w3,
                                                 unsigned short* __restrict__ o0, unsigned short* __restrict__ o1,
                                                 unsigned short* __restrict__ o2, unsigned short* __restrict__ o3) {
  __shared__ float tile[64][65];
  int bid = blockIdx.x;
  const float* W; unsigned short* Wt; int K, N, tx;
  if (bid < 768)       { W = w0; Wt = o0; K = 1024; N = 3072; tx = 48; }
  else if (bid < 1024) { bid -= 768;  W = w1; Wt = o1; K = 1024; N = 1024; tx = 16; }
  else if (bid < 2048) { bid -= 1024; W = w2; Wt = o2; K = 1024; N = 4096; tx = 64; }
  else                 { bid -= 2048; W = w3; Wt = o3; K = 4096; N = 1024; tx = 16; }
  const int kt = (bid / tx) * 64, nt = (bid % tx) * 64;
  const int t = threadIdx.x;
#pragma unroll
  for (int p = 0; p < 4; p++) {
    int kr = p * 16 + (t >> 4);
    int nc = (t & 15) * 4;
    float4 v = *(const float4*)&W[(size_t)(kt + kr) * N + nt + nc];
    tile[kr][nc] = v.x; tile[kr][nc + 1] = v.y; tile[kr][nc + 2] = v.z; tile[kr][nc + 3] = v.w;
  }
  __syncthreads();
  const int nr = t >> 2, kc = (t & 3) * 16;
  unsigned int u[8];
#pragma unroll
  for (int i = 0; i < 8; i++)
    u[i] = (unsigned int)f2bf(tile[kc + 2 * i][nr]) | ((unsigned int)f2bf(tile[kc + 2 * i + 1][nr]) << 16);
  uint4 q0; q0.x = u[0]; q0.y = u[1]; q0.z = u[2]; q0.w = u[3];
  uint4 q1; q1.x = u[4]; q1.y = u[5]; q1.z = u[6]; q1.w = u[7];
  *(uint4*)&Wt[(size_t)(nt + nr) * K + kt + kc] = q0;
  *(uint4*)&Wt[(size_t)(nt + nr) * K + kt + kc + 8] = q1;
}

// ---------- LayerNorm: fp32 in, bf16 out ----------
__global__ __launch_bounds__(256) void ln_kernel(const float* __restrict__ x,
                                                 const float* __restrict__ g,
                                                 const float* __restrict__ be,
                                                 unsigned short* __restrict__ out) {
  const int row = blockIdx.x;
  const int t = threadIdx.x;
  const float4* xp = (const float4*)(x + (size_t)row * Dc);
  float4 v = xp[t];
  float s = v.x + v.y + v.z + v.w;
  float s2 = v.x * v.x + v.y * v.y + v.z * v.z + v.w * v.w;
#pragma unroll
  for (int off = 32; off; off >>= 1) {
    s += __shfl_down(s, off);
    s2 += __shfl_down(s2, off);
  }
  __shared__ float rs[4], rs2[4];
  if ((t & 63) == 0) { rs[t >> 6] = s; rs2[t >> 6] = s2; }
  __syncthreads();
  float S = rs[0] + rs[1] + rs[2] + rs[3];
  float S2 = rs2[0] + rs2[1] + rs2[2] + rs2[3];
  float mean = S * (1.0f / Dc);
  float var = S2 * (1.0f / Dc) - mean * mean;
  float rstd = rsqrtf(var + 1e-5f);
  float4 gv = ((const float4*)g)[t];
  float4 bv = ((const float4*)be)[t];
  float o0 = (v.x - mean) * rstd * gv.x + bv.x;
  float o1 = (v.y - mean) * rstd * gv.y + bv.y;
  float o2 = (v.z - mean) * rstd * gv.z + bv.z;
  float o3 = (v.w - mean) * rstd * gv.w + bv.w;
  uint2 pk;
  pk.x = (unsigned int)f2bf(o0) | ((unsigned int)f2bf(o1) << 16);
  pk.y = (unsigned int)f2bf(o2) | ((unsigned int)f2bf(o3) << 16);
  *(uint2*)(out + (size_t)row * Dc + t * 4) = pk;
}

// ---------- bf16 MFMA GEMM, templated BM (128 or 64), BN=128 ----------
// dbuf LDS, one barrier/K-step, stage-after-barrier overlap, XCD column-stripe remap.
// flags: 1=+bias, 2=exact GELU, 4=+resid(fp32), 8=write bf16 to aux, 16=qkv split write
// qkv split layouts (all bf16, per bh = b*Hc+h, 131072 elems per bh per tensor):
//   Q : natural [bh][t][d]
//   KF: [bh][kg=t>>4][chunk=d>>3][c=t&15][8]
//   VF: [bh][kt=t>>6][d4=d>>4][half][g'][c=d&15][j] with a=tt&63:
//       half=(a>>5)&1, g'=(a>>2)&3, j=((a>>4)&1)*4+(a&3)   <- pi(k) baked for in-reg P
template<int BM>
__global__ __launch_bounds__(256) void gemm_bf16(const unsigned short* __restrict__ A,
                                                 const unsigned short* __restrict__ Wt,
                                                 const float* __restrict__ bias,
                                                 const float* __restrict__ resid,
                                                 float* __restrict__ C,
                                                 unsigned short* __restrict__ aux,
                                                 int M, int N, int K, int flags) {
  constexpr int BN = 128;
  constexpr int NW = (BM == 128) ? 2 : 4;   // waves along N
  constexpr int WN = BN / NW;               // 64 or 32 cols per wave
  constexpr int NFR = WN / 16;              // 4 or 2 col-frags
  constexpr int ALOADS = BM / 64;           // staging iterations for A
  __shared__ alignas(16) unsigned short As[2][BM][32];
  __shared__ alignas(16) unsigned short Bs[2][BN][32];
  const int t = threadIdx.x;
  const int lane = t & 63, wave = t >> 6;
  const int wr = (BM == 128) ? (wave >> 1) : 0;
  const int wc = (BM == 128) ? (wave & 1) : wave;
  const int c = lane & 15, g = lane >> 4;

  // XCD column-stripe remap (bijective; all grids have nwg % 8 == 0)
  const int gx = N / BN;
  const int sw = gx >> 3;                   // x-stripe width per XCD
  const int bid = blockIdx.x;
  const int xcd = bid & 7, lid = bid >> 3;
  const int lx = xcd * sw + lid % sw;
  const int ly = lid / sw;
  const int row0 = ly * BM, col0 = lx * BN;

  f32x4 acc[4][NFR];
#pragma unroll
  for (int m = 0; m < 4; m++)
#pragma unroll
    for (int n = 0; n < NFR; n++) acc[m][n] = (f32x4){0.f, 0.f, 0.f, 0.f};

  auto stage = [&](int k0, int buf) {
    char* AsB = (char*)&As[buf][0][0] + wave * 1024;
    char* BsB = (char*)&Bs[buf][0][0] + wave * 1024;
#pragma unroll
    for (int i = 0; i < ALOADS; i++) {
      int l = t + 256 * i;
      gload16(A + (size_t)(row0 + (l >> 2)) * K + k0 + (l & 3) * 8, AsB + i * 4096);
    }
#pragma unroll
    for (int i = 0; i < 2; i++) {
      int l = t + 256 * i;
      gload16(Wt + (size_t)(col0 + (l >> 2)) * K + k0 + (l & 3) * 8, BsB + i * 4096);
    }
  };

  const int nk = K / 32;
  stage(0, 0);
  for (int ki = 0; ki < nk; ki++) {
    const int buf = ki & 1;
    __syncthreads();                          // stage(ki) complete; buf readable
    if (ki + 1 < nk) stage((ki + 1) * 32, buf ^ 1);   // in flight under compute
    const char* Ab = (const char*)&As[buf][0][0];
    const char* Bb = (const char*)&Bs[buf][0][0];
    bf16x8 af[4], bfv[NFR];
#pragma unroll
    for (int m = 0; m < 4; m++) af[m] = *(const bf16x8*)(Ab + (wr * 64 + m * 16 + c) * 64 + g * 16);
#pragma unroll
    for (int n = 0; n < NFR; n++) bfv[n] = *(const bf16x8*)(Bb + (wc * WN + n * 16 + c) * 64 + g * 16);
#pragma unroll
    for (int m = 0; m < 4; m++)
#pragma unroll
      for (int n = 0; n < NFR; n++)
        acc[m][n] = __builtin_amdgcn_mfma_f32_16x16x32_bf16(af[m], bfv[n], acc[m][n], 0, 0, 0);
  }

#pragma unroll
  for (int m = 0; m < 4; m++) {
    const int row = row0 + wr * 64 + m * 16 + g * 4;
#pragma unroll
    for (int n = 0; n < NFR; n++) {
      const int col = col0 + wc * WN + n * 16 + c;
      const float bi = (flags & 1) ? bias[col] : 0.0f;
#pragma unroll
      for (int r = 0; r < 4; r++) {
        float v = acc[m][n][r] + bi;
        if (flags & 2) v = 0.5f * v * (1.0f + erff(v * 0.70710678118654752f));
        if (flags & 4) v += resid[(size_t)(row + r) * N + col];
        if (flags & 16) {
          int rr = row + r;
          int b = rr >> 11, tt = rr & 2047;
          int s = col >> 10, wcol = col & 1023;
          int h = wcol >> 6, f = wcol & 63;
          size_t base = ((size_t)(b * Hc + h)) * 131072;
          unsigned short bv = f2bf(v);
          if (s == 0) {
            aux[base + (size_t)tt * HDc + f] = bv;                       // Q natural
          } else if (s == 1) {
            aux[4194304 + base + (size_t)(tt >> 4) * 1024 + (f >> 3) * 128 + (tt & 15) * 8 + (f & 7)] = bv;
          } else {
            // VF with pi(k) permutation baked in
            int a = tt & 63;
            int j = (((a >> 4) & 1) << 2) | (a & 3);
            aux[8388608 + base + (size_t)(tt >> 6) * 4096 + (f >> 4) * 1024 +
                ((a >> 5) & 1) * 512 + ((a >> 2) & 3) * 128 + (f & 15) * 8 + j] = bv;
          }
        } else if (flags & 8) {
          aux[(size_t)(row + r) * N + col] = f2bf(v);
        } else {
          C[(size_t)(row + r) * N + col] = v;
        }
      }
    }
  }
}

// ---------- MFMA flash attention v5: swapped QK^T, in-register P (no LDS) ----------
// Qb: [32 bh][2048][64] bf16 ; KF,VF: fragment order (see gemm epilogue) ; Ob: [B][T][D] bf16
// Per wave: 16 q-rows. Swapped QK (A=K, B=Q) -> lane (c,g) holds scores for q=c,
// keys i*16+g*4+r. Softmax state (m,l) lives in the q=c domain; PV A-frag packed
// lane-locally via v_cvt_pk_bf16_f32 (formal kk permutation pi matches VF layout).
__global__ __launch_bounds__(256, 4) void fattn(const unsigned short* __restrict__ Qb,
                                                const unsigned short* __restrict__ KF,
                                                const unsigned short* __restrict__ VF,
                                                unsigned short* __restrict__ Ob) {
  const int t = threadIdx.x, wave = t >> 6, lane = t & 63;
  const int c = lane & 15, g = lane >> 4;
  const int bid = blockIdx.x;
  const int bh = ((bid & 7) << 2) | ((bid >> 3) & 3);   // XCD-local bh groups
  const int qt = bid >> 5;
  const int q0 = qt * 64 + wave * 16;

  const unsigned short* Qp = Qb + ((size_t)bh * Tc + q0) * HDc;
  const unsigned short* Kp = KF + (size_t)bh * 131072;   // [kg][chunk][c][8]
  const unsigned short* Vp = VF + (size_t)bh * 131072;   // [ktile][d4][half][g'][c][j], pi-permuted

  const bf16x8 qf0 = *(const bf16x8*)(Qp + c * HDc + g * 8);
  const bf16x8 qf1 = *(const bf16x8*)(Qp + c * HDc + 32 + g * 8);

  const f32x4 z = {0.f, 0.f, 0.f, 0.f};
  f32x4 o[4] = {z, z, z, z};
  float m = -3e38f;                                // running max (scaled), q=c domain
  float l = 0.f;                                   // per-lane partial denom (16 keys/tile)
  const float Cs = 0.125f * 1.4426950408889634f;   // (1/sqrt(64)) * log2(e)
  const int lofs = lane * 8;

  auto loadK = [&](int kt, bf16x8 (&K)[4][2]) {
    const unsigned short* kb = Kp + (kt >> 4) * 1024 + lofs;
#pragma unroll
    for (int i = 0; i < 4; i++) {
      K[i][0] = *(const bf16x8*)(kb + i * 1024);
      K[i][1] = *(const bf16x8*)(kb + i * 1024 + 512);
    }
  };

  auto tile = [&](int kt, bf16x8 (&K)[4][2]) {
    f32x4 s[4];
#pragma unroll
    for (int i = 0; i < 4; i++) {                  // swapped: A=K, B=Q -> C[key][q]
      s[i] = __builtin_amdgcn_mfma_f32_16x16x32_bf16(K[i][0], qf0, z, 0, 0, 0);
      s[i] = __builtin_amdgcn_mfma_f32_16x16x32_bf16(K[i][1], qf1, s[i], 0, 0, 0);
    }
    // V loads issued now, consumed after softmax (~300 cyc slack)
    const unsigned short* vb = Vp + (kt >> 6) * 4096 + lofs;
    bf16x8 v0[4], v1[4];
#pragma unroll
    for (int d4 = 0; d4 < 4; d4++) {
      v0[d4] = *(const bf16x8*)(vb + d4 * 1024);
      v1[d4] = *(const bf16x8*)(vb + d4 * 1024 + 512);
    }

    // lane-local max over this lane's 16 scores (raw domain)
    float lm = fmaxf(fmaxf(s[0][0], s[0][1]), fmaxf(s[0][2], s[0][3]));
#pragma unroll
    for (int i = 1; i < 4; i++)
      lm = fmaxf(lm, fmaxf(fmaxf(s[i][0], s[i][1]), fmaxf(s[i][2], s[i][3])));
    const float lms = lm * Cs;

    if (!__all(lms <= m + 8.0f)) {                 // rare rescale path (T13)
      float mx = fmaxf(lms, __shfl_xor(lms, 16));
      mx = fmaxf(mx, __shfl_xor(mx, 32));          // row max for q=c (4 partner lanes)
      float nm = fmaxf(m, mx);
      float ef = exp2f(m - nm);
      m = nm;
      l *= ef;
#pragma unroll
      for (int r = 0; r < 4; r++) {                // o rows are q=g*4+r: pull ef cross-lane
        float efr = __shfl(ef, g * 4 + r);
        o[0][r] *= efr; o[1][r] *= efr; o[2][r] *= efr; o[3][r] *= efr;
      }
    }

    // p = exp2(s*Cs - m), in place; accumulate partial l
    float psum = 0.f;
#pragma unroll
    for (int i = 0; i < 4; i++) {
#pragma unroll
      for (int r = 0; r < 4; r++) {
        s[i][r] = exp2f(fmaf(s[i][r], Cs, -m));
        psum += s[i][r];
      }
    }
    l += psum;

    // pack PV A-fragments lane-locally (formal kk = (i>>1)*32 + g*8 + (i&1)*4 + r)
    union { unsigned int w[4]; bf16x8 v; } pk0, pk1;
    pk0.w[0] = cvtpk(s[0][0], s[0][1]); pk0.w[1] = cvtpk(s[0][2], s[0][3]);
    pk0.w[2] = cvtpk(s[1][0], s[1][1]); pk0.w[3] = cvtpk(s[1][2], s[1][3]);
    pk1.w[0] = cvtpk(s[2][0], s[2][1]); pk1.w[1] = cvtpk(s[2][2], s[2][3]);
    pk1.w[2] = cvtpk(s[3][0], s[3][1]); pk1.w[3] = cvtpk(s[3][2], s[3][3]);

#pragma unroll
    for (int d4 = 0; d4 < 4; d4++) {
      o[d4] = __builtin_amdgcn_mfma_f32_16x16x32_bf16(pk0.v, v0[d4], o[d4], 0, 0, 0);
      o[d4] = __builtin_amdgcn_mfma_f32_16x16x32_bf16(pk1.v, v1[d4], o[d4], 0, 0, 0);
    }
  };

  bf16x8 kA[4][2], kB[4][2];
  loadK(0, kA);
  for (int kt = 0; kt < Tc; kt += 128) {
    loadK(kt + 64, kB);
    tile(kt, kA);
    loadK((kt + 128) & (Tc - 1), kA);   // wraps to 0 on last iter (valid, unused)
    tile(kt + 64, kB);
  }

  // denom: reduce partial l across the 4 partner lanes of q=c, then distribute
  l += __shfl_xor(l, 16);
  l += __shfl_xor(l, 32);
  const float linv = 1.0f / l;
  float linvr[4];
#pragma unroll
  for (int r = 0; r < 4; r++) linvr[r] = __shfl(linv, g * 4 + r);

  const int b = bh >> 4, h = bh & 15;
#pragma unroll
  for (int r = 0; r < 4; r++) {
    size_t rowoff = ((size_t)b * Tc + q0 + g * 4 + r) * Dc + h * HDc + c;
    Ob[rowoff + 0]  = f2bf(o[0][r] * linvr[r]);
    Ob[rowoff + 16] = f2bf(o[1][r] * linvr[r]);
    Ob[rowoff + 32] = f2bf(o[2][r] * linvr[r]);
    Ob[rowoff + 48] = f2bf(o[3][r] * linvr[r]);
  }
}

extern "C" void kernel_launch(void* const* d_in, const int* in_sizes, int n_in,
                              void* d_out, int out_size, void* d_ws, size_t ws_size,
                              hipStream_t stream) {
  const float* x     = (const float*)d_in[0];
  const float* w_qkv = (const float*)d_in[1];
  const float* w_out = (const float*)d_in[2];
  const float* w_ff1 = (const float*)d_in[3];
  const float* b_ff1 = (const float*)d_in[4];
  const float* w_ff2 = (const float*)d_in[5];
  const float* b_ff2 = (const float*)d_in[6];
  const float* g1    = (const float*)d_in[7];
  const float* be1   = (const float*)d_in[8];
  const float* g2    = (const float*)d_in[9];
  const float* be2   = (const float*)d_in[10];

  char* ws = (char*)d_ws;
  unsigned short* qkvb  = (unsigned short*)ws;                          // Q|KF|VF bf16, 24 MB [0,24)
  unsigned short* xn    = (unsigned short*)(ws + ((size_t)24 << 20));   // 8 MB  [24,32)
  unsigned short* Ob    = (unsigned short*)(ws + ((size_t)32 << 20));   // 8 MB  [32,40)
  unsigned short* hbuf  = (unsigned short*)(ws + ((size_t)40 << 20));   // 32 MB [40,72)
  unsigned short* wqkvT = (unsigned short*)(ws + ((size_t)72 << 20));   // 6 MB
  unsigned short* woutT = (unsigned short*)(ws + ((size_t)78 << 20));   // 2 MB
  unsigned short* wff1T = (unsigned short*)(ws + ((size_t)80 << 20));   // 8 MB
  unsigned short* wff2T = (unsigned short*)(ws + ((size_t)88 << 20));   // 8 MB -> 96 MB total
  float* x2 = (float*)d_out;   // fp32 residual scratch, overwritten by ff2 at the end

  dim3 blk(256);
  // all four weight transposes in one launch
  wconv_all<<<3072, blk, 0, stream>>>(w_qkv, w_out, w_ff1, w_ff2, wqkvT, woutT, wff1T, wff2T);

  // xn = LN(x) in bf16
  ln_kernel<<<Mc, blk, 0, stream>>>(x, g1, be1, xn);
  // qkv GEMM with fragment-ordered Q/KF/VF epilogue
  gemm_bf16<128><<<768, blk, 0, stream>>>(xn, wqkvT, nullptr, nullptr, nullptr, qkvb,
                                          Mc, 3 * Dc, Dc, 16);
  // flash attention
  fattn<<<dim3(1024), blk, 0, stream>>>(qkvb, qkvb + 4194304, qkvb + 8388608, Ob);
  // x2 = x + attn @ w_out   (fp32 into d_out); BM=64 -> 512 blocks
  gemm_bf16<64><<<512, blk, 0, stream>>>(Ob, woutT, nullptr, x, x2, nullptr,
                                         Mc, Dc, Dc, 4);
  // xn = LN(x2) in bf16
  ln_kernel<<<Mc, blk, 0, stream>>>(x2, g2, be2, xn);
  // h = gelu(xn @ w_ff1 + b1) in bf16
  gemm_bf16<128><<<1024, blk, 0, stream>>>(xn, wff1T, b_ff1, nullptr, nullptr, hbuf,
                                           Mc, 4 * Dc, Dc, 1 | 2 | 8);
  // out = x2 + h @ w_ff2 + b2  (fp32); BM=64 -> 512 blocks
  gemm_bf16<64><<<512, blk, 0, stream>>>(hbuf, wff2T, b_ff2, x2, (float*)d_out, nullptr,
                                         Mc, Dc, 4 * Dc, 1 | 4);
}